// Round 9
// baseline (249.750 us; speedup 1.0000x reference)
//
#include <hip/hip_runtime.h>
#include <float.h>

#define NV 4096
#define OSTRIDE 451
#define NT 256
typedef unsigned long long u64;

// key = (float-bits(d2) << 32) | idx. d2 >= 0 so float bits are monotone in
// value -> u64 compare == exact lexicographic (d2, idx) compare == top_k's
// stable tie semantics.
__device__ __forceinline__ u64 packkey(float d, int idx) {
    return ((u64)__float_as_uint(d) << 32) | (u64)(unsigned)idx;
}

__device__ __forceinline__ void cswap(u64& a, u64& b) {
    bool c = a < b;
    u64 lo = c ? a : b;
    u64 hi = c ? b : a;
    a = lo; b = hi;
}

// sorted ascending insert of ck (caller guarantees ck < k[7]); drops k[7]
__device__ __forceinline__ void ins8(u64 (&k)[8], u64 ck) {
    bool b[7];
#pragma unroll
    for (int q = 0; q < 7; ++q) b[q] = ck < k[q];
#pragma unroll
    for (int q = 7; q >= 1; --q) {
        bool hi = (q == 7) ? true : b[q];
        k[q] = b[q-1] ? k[q-1] : (hi ? ck : k[q]);
    }
    k[0] = b[0] ? ck : k[0];
}

// wave-uniform event loop with post-insert refilter (prunes seed storms)
__device__ __forceinline__ void handle8(u64 mask, float dj, int jj, int ob,
                                        u64 (&k)[8], float& T) {
    while (mask) {
        int l = __builtin_ctzll(mask);
        mask &= mask - 1;
        int cm = ob + 8*l + jj;
        if (cm < 8) continue;                      // seed points already in list
        float cd = __uint_as_float(__builtin_amdgcn_readlane(__float_as_uint(dj), l));
        u64 ck = packkey(cd, cm);
        if (ck < k[7]) {
            ins8(k, ck);
            T = __uint_as_float((unsigned)(k[7] >> 32));
            mask &= __ballot(dj <= T);             // refilter vs tightened T
        }
    }
}

// weight: reference recomputes dist2 from vec = nbr - vert, numpy op order
// (round products, sequential add, no fma), w = 1/(1+dist2)
template<int M>
__device__ __forceinline__ float wcalc(const float* __restrict__ pc, int m,
                                       float vx, float vy, float vz) {
    float qx = pc[m], qy = pc[M+m], qz = pc[2*M+m];
    float dx = __fsub_rn(qx, vx), dy = __fsub_rn(qy, vy), dz = __fsub_rn(qz, vz);
    float dist2 = __fadd_rn(__fadd_rn(__fmul_rn(dx,dx), __fmul_rn(dy,dy)),
                            __fmul_rn(dz,dz));
    return __fdiv_rn(1.0f, __fadd_rn(1.0f, dist2));
}

// One wave, ONE (vertex, stage) pair, full scan (PARTS=1: minimal events, no
// merges, no LDS, no barriers). Lanes process 8 consecutive points per
// 512-point batch (6 float4 loads, 1-deep prefetch). Top-8 = wave-uniform
// u64 keys; all branches wave-uniform. Selection distance = direct form
// (p-v).(p-v): abs err ~ulp(d2), ~500x tighter than the reference's
// cancellation form -> matches the f64-arbiter ordering.
template<int M, int DF, int COFF, bool TR>
__device__ __forceinline__ void stage1v(
    const float* __restrict__ verts,
    const float* __restrict__ pc,     // [3*M]
    const float* __restrict__ feat,   // [DF*M] (fallback gather)
    const float* __restrict__ featT,  // [M*DF] (transposed gather)
    float* __restrict__ out,
    int n, int lane)
{
    const float vx = verts[n*3+0], vy = verts[n*3+1], vz = verts[n*3+2];

    // seed: exact keys of points 0..7, sorted (Batcher 19-comparator network)
    u64 kk[8];
    {
#pragma unroll
        for (int q = 0; q < 8; ++q) {
            float dx=__fsub_rn(pc[q],vx), dy=__fsub_rn(pc[M+q],vy), dz=__fsub_rn(pc[2*M+q],vz);
            float d = __fmaf_rn(dz,dz,__fmaf_rn(dy,dy,__fmul_rn(dx,dx)));
            kk[q] = packkey(d, q);
        }
        cswap(kk[0],kk[1]); cswap(kk[2],kk[3]); cswap(kk[4],kk[5]); cswap(kk[6],kk[7]);
        cswap(kk[0],kk[2]); cswap(kk[1],kk[3]); cswap(kk[4],kk[6]); cswap(kk[5],kk[7]);
        cswap(kk[1],kk[2]); cswap(kk[5],kk[6]);
        cswap(kk[0],kk[4]); cswap(kk[1],kk[5]); cswap(kk[2],kk[6]); cswap(kk[3],kk[7]);
        cswap(kk[2],kk[4]); cswap(kk[3],kk[5]);
        cswap(kk[1],kk[2]); cswap(kk[3],kk[4]); cswap(kk[5],kk[6]);
    }
    float T = __uint_as_float((unsigned)(kk[7] >> 32));

    const float* __restrict__ px = pc;
    const float* __restrict__ py = pc + M;
    const float* __restrict__ pz = pc + 2*M;

    // 512-pt batches: lane owns points 8*lane .. 8*lane+7
    float4 Xa = *(const float4*)(px + 8*lane), Xb = *(const float4*)(px + 8*lane + 4);
    float4 Ya = *(const float4*)(py + 8*lane), Yb = *(const float4*)(py + 8*lane + 4);
    float4 Za = *(const float4*)(pz + 8*lane), Zb = *(const float4*)(pz + 8*lane + 4);
    for (int ob = 0; ob < M; ob += 512) {
        int nb = (ob + 512 < M) ? ob + 512 : 0;     // last prefetch dead
        float4 nXa = *(const float4*)(px + nb + 8*lane), nXb = *(const float4*)(px + nb + 8*lane + 4);
        float4 nYa = *(const float4*)(py + nb + 8*lane), nYb = *(const float4*)(py + nb + 8*lane + 4);
        float4 nZa = *(const float4*)(pz + nb + 8*lane), nZb = *(const float4*)(pz + nb + 8*lane + 4);
        float d0, d1, d2, d3, d4, d5, d6, d7;
        {
            float dx, dy, dz;
            dx=__fsub_rn(Xa.x,vx); dy=__fsub_rn(Ya.x,vy); dz=__fsub_rn(Za.x,vz);
            d0=__fmaf_rn(dz,dz,__fmaf_rn(dy,dy,__fmul_rn(dx,dx)));
            dx=__fsub_rn(Xa.y,vx); dy=__fsub_rn(Ya.y,vy); dz=__fsub_rn(Za.y,vz);
            d1=__fmaf_rn(dz,dz,__fmaf_rn(dy,dy,__fmul_rn(dx,dx)));
            dx=__fsub_rn(Xa.z,vx); dy=__fsub_rn(Ya.z,vy); dz=__fsub_rn(Za.z,vz);
            d2=__fmaf_rn(dz,dz,__fmaf_rn(dy,dy,__fmul_rn(dx,dx)));
            dx=__fsub_rn(Xa.w,vx); dy=__fsub_rn(Ya.w,vy); dz=__fsub_rn(Za.w,vz);
            d3=__fmaf_rn(dz,dz,__fmaf_rn(dy,dy,__fmul_rn(dx,dx)));
            dx=__fsub_rn(Xb.x,vx); dy=__fsub_rn(Yb.x,vy); dz=__fsub_rn(Zb.x,vz);
            d4=__fmaf_rn(dz,dz,__fmaf_rn(dy,dy,__fmul_rn(dx,dx)));
            dx=__fsub_rn(Xb.y,vx); dy=__fsub_rn(Yb.y,vy); dz=__fsub_rn(Zb.y,vz);
            d5=__fmaf_rn(dz,dz,__fmaf_rn(dy,dy,__fmul_rn(dx,dx)));
            dx=__fsub_rn(Xb.z,vx); dy=__fsub_rn(Yb.z,vy); dz=__fsub_rn(Zb.z,vz);
            d6=__fmaf_rn(dz,dz,__fmaf_rn(dy,dy,__fmul_rn(dx,dx)));
            dx=__fsub_rn(Xb.w,vx); dy=__fsub_rn(Yb.w,vy); dz=__fsub_rn(Zb.w,vz);
            d7=__fmaf_rn(dz,dz,__fmaf_rn(dy,dy,__fmul_rn(dx,dx)));
        }
        u64 m0 = __ballot(d0 <= T), m1 = __ballot(d1 <= T);
        u64 m2 = __ballot(d2 <= T), m3 = __ballot(d3 <= T);
        u64 m4 = __ballot(d4 <= T), m5 = __ballot(d5 <= T);
        u64 m6 = __ballot(d6 <= T), m7 = __ballot(d7 <= T);
        if (m0|m1|m2|m3|m4|m5|m6|m7) {              // wave-uniform rare path
            handle8(m0, d0, 0, ob, kk, T);
            handle8(m1, d1, 1, ob, kk, T);
            handle8(m2, d2, 2, ob, kk, T);
            handle8(m3, d3, 3, ob, kk, T);
            handle8(m4, d4, 4, ob, kk, T);
            handle8(m5, d5, 5, ob, kk, T);
            handle8(m6, d6, 6, ob, kk, T);
            handle8(m7, d7, 7, ob, kk, T);
        }
        Xa = nXa; Xb = nXb; Ya = nYa; Yb = nYb; Za = nZa; Zb = nZb;
    }

    // weights + feature mean, wave-local (no LDS)
    int m8[8]; float w8[8];
#pragma unroll
    for (int k = 0; k < 8; ++k) {
        int m = (int)(kk[k] & 0xFFFFFFFFu);
        m8[k] = m;
        w8[k] = wcalc<M>(pc, m, vx, vy, vz);
    }
    for (int f = lane; f < DF; f += 64) {
        float e[8];
#pragma unroll
        for (int k = 0; k < 8; ++k) {
            float fv = TR ? featT[m8[k]*DF + f] : feat[f*M + m8[k]];
            e[k] = __fmul_rn(w8[k], fv);
        }
        float s = __fadd_rn(__fadd_rn(__fadd_rn(e[0],e[1]), __fadd_rn(e[2],e[3])),
                            __fadd_rn(__fadd_rn(e[4],e[5]), __fadd_rn(e[6],e[7])));
        out[n*OSTRIDE + COFF + f] = __fmul_rn(0.125f, s);
    }
}

// LDS-tiled transpose: feat [Df, M] -> featT [M, Df]; BOTH sides coalesced.
// 64x64 tiles; 1536 blocks total (512 per stage).
__global__ __launch_bounds__(256)
void tr_kernel(const float* __restrict__ f1, const float* __restrict__ f2,
               const float* __restrict__ f3, float* __restrict__ ws)
{
    __shared__ float s[64][65];
    int b = blockIdx.x;
    const float* src; float* dst; int M, DF, tm, tf;
    if (b < 512)       { src = f1; dst = ws;           M = 32768; DF = 64;  tm = b & 511;        tf = b >> 9; }
    else if (b < 1024) { src = f2; dst = ws + 2097152; M = 16384; DF = 128; tm = (b-512) & 255;  tf = (b-512) >> 8; }
    else               { src = f3; dst = ws + 4194304; M = 8192;  DF = 256; tm = (b-1024) & 127; tf = (b-1024) >> 7; }
    const int mb = tm*64, fb = tf*64;
    const int tid = threadIdx.x;
    const int a0 = tid & 63, a1 = tid >> 6;
#pragma unroll
    for (int i = 0; i < 16; ++i) {                  // read: lanes along m
        int ff = a1 + i*4;
        s[ff][a0] = src[(fb+ff)*M + mb + a0];
    }
    __syncthreads();
#pragma unroll
    for (int i = 0; i < 16; ++i) {                  // write: lanes along f
        int mm2 = a1 + i*4;
        dst[(mb+mm2)*DF + fb + a0] = s[a0][mm2];
    }
}

// Grid: 3072 scan blocks = (vertex-group, stage) pairs, stage = b%3 so
// consecutive blocks (and hence each CU) get a stage mix. 4 waves/block,
// 1 vertex per wave -> 12288 independent waves. + 1 coord-copy block.
template<bool TR>
__global__ __launch_bounds__(NT, 8)
void gp_kernel(const float* __restrict__ verts,
               const float* __restrict__ pc1, const float* __restrict__ f1,
               const float* __restrict__ pc2, const float* __restrict__ f2,
               const float* __restrict__ pc3, const float* __restrict__ f3,
               const float* __restrict__ ws,
               float* __restrict__ out)
{
    int b = blockIdx.x;
    if (b < 3072) {
        const int lane  = threadIdx.x & 63;
        const int stage = b % 3;
        const int n     = (b / 3) * 4 + (threadIdx.x >> 6);
        if (stage == 0) {
            stage1v<32768,  64,   3, TR>(verts, pc1, f1, ws,           out, n, lane);
        } else if (stage == 1) {
            stage1v<16384, 128,  67, TR>(verts, pc2, f2, ws + 2097152, out, n, lane);
        } else {
            stage1v< 8192, 256, 195, TR>(verts, pc3, f3, ws + 4194304, out, n, lane);
        }
    } else {
        for (int i = threadIdx.x; i < NV*3; i += NT)
            out[(i/3)*OSTRIDE + (i % 3)] = verts[i];
    }
}

extern "C" void kernel_launch(void* const* d_in, const int* in_sizes, int n_in,
                              void* d_out, int out_size, void* d_ws, size_t ws_size,
                              hipStream_t stream) {
    const float* verts = (const float*)d_in[0];
    // d_in[1] = pc0_coords: unused (reference discards stage 0)
    const float* pc1 = (const float*)d_in[2];
    const float* f1  = (const float*)d_in[3];
    const float* pc2 = (const float*)d_in[4];
    const float* f2  = (const float*)d_in[5];
    const float* pc3 = (const float*)d_in[6];
    const float* f3  = (const float*)d_in[7];
    float* out = (float*)d_out;
    float* ws  = (float*)d_ws;

    if (ws_size >= 6291456u * sizeof(float)) {
        tr_kernel<<<1536, 256, 0, stream>>>(f1, f2, f3, ws);
        gp_kernel<true><<<3073, NT, 0, stream>>>(verts, pc1, f1, pc2, f2, pc3, f3, ws, out);
    } else {
        gp_kernel<false><<<3073, NT, 0, stream>>>(verts, pc1, f1, pc2, f2, pc3, f3, ws, out);
    }
}